// Round 5
// baseline (1213.956 us; speedup 1.0000x reference)
//
#include <hip/hip_runtime.h>

// QuantizerEncoder: code[n,h,w,m] = argmax_k < wq[m] @ q_raw[n,h,w,m], wk[m] @ cb[m,k] >
// n=16, d=512, h=64, w=64, m=4, kcodes=256, dm=128
//
// Round 4: same algorithm as R3 (fold Wq into keys -> keff; fp32 fast argmax + fp64
// rescue of near-ties). Key change: pin qr[128] into VGPRs with an empty
// `asm volatile("" : "+v")` per element. R2/R3 both landed at VGPR_Count=72 --
// LLVM rematerializes loop-invariant global loads instead of keeping them live,
// so q was re-fetched from cache inside the k-loop (VALU 4.6x the FMA-only count).
// The asm is an opaque def: non-duplicable, non-sinkable -> q stays register-resident
// and the k-loop is pure v_fmac_f32 v_acc, s_keff, v_q.

#define MM   4
#define KC   256
#define DM   128
#define HW   4096   // h*w
#define NTOT 16
#define HH   64
#define WW_  64
#define EPS  2e-3f
#define WL_CAP 65536

// ---- Kernel 1: A[m][e][d] = sum_c wk[m][c][e] * wq[m][c][d]  (fp64) ----
__global__ __launch_bounds__(128) void a_kernel(const float* __restrict__ wk,
                                                const float* __restrict__ wq,
                                                double* __restrict__ A) {
    int me = blockIdx.x;           // m*128 + e
    int d  = threadIdx.x;
    int m  = me >> 7;
    int e  = me & 127;
    const float* wkm = wk + (size_t)m * DM * DM + e;       // wk[m][c][e], stride DM
    const float* wqm = wq + (size_t)m * DM * DM + d;       // wq[m][c][d], stride DM
    double s0 = 0.0, s1 = 0.0, s2 = 0.0, s3 = 0.0;
#pragma unroll 8
    for (int c = 0; c < DM; c += 4) {
        s0 = fma((double)wkm[(size_t)(c+0) * DM], (double)wqm[(size_t)(c+0) * DM], s0);
        s1 = fma((double)wkm[(size_t)(c+1) * DM], (double)wqm[(size_t)(c+1) * DM], s1);
        s2 = fma((double)wkm[(size_t)(c+2) * DM], (double)wqm[(size_t)(c+2) * DM], s2);
        s3 = fma((double)wkm[(size_t)(c+3) * DM], (double)wqm[(size_t)(c+3) * DM], s3);
    }
    A[(size_t)me * DM + d] = (s0 + s1) + (s2 + s3);
}

// ---- Kernel 2: keff[m][k][d] = sum_e cb[m][k][e] * A[m][e][d]  (fp64 + fp32 copy) ----
__global__ __launch_bounds__(128) void keff_kernel(const float* __restrict__ cb,
                                                   const double* __restrict__ A,
                                                   double* __restrict__ keffd,
                                                   float* __restrict__ keff32) {
    int mk = blockIdx.x;           // m*256 + k
    int d  = threadIdx.x;
    int m  = mk >> 8;
    const float*  cbr = cb + (size_t)mk * DM;              // cb[m][k][*]
    const double* Am  = A + (size_t)m * DM * DM + d;       // A[m][e][d], stride DM
    double s0 = 0.0, s1 = 0.0, s2 = 0.0, s3 = 0.0;
#pragma unroll 8
    for (int e = 0; e < DM; e += 4) {
        s0 = fma((double)cbr[e+0], Am[(size_t)(e+0) * DM], s0);
        s1 = fma((double)cbr[e+1], Am[(size_t)(e+1) * DM], s1);
        s2 = fma((double)cbr[e+2], Am[(size_t)(e+2) * DM], s2);
        s3 = fma((double)cbr[e+3], Am[(size_t)(e+3) * DM], s3);
    }
    double s = (s0 + s1) + (s2 + s3);
    keffd[(size_t)mk * DM + d]  = s;
    keff32[(size_t)mk * DM + d] = (float)s;
}

// ---- Kernel 3: fp32 argmax with near-tie detection ----
// block = 256: w = tid&63 (coalesced lanes), m = tid>>6 (one wave per group)
__global__ __launch_bounds__(256, 2) void argmax_fast(const float* __restrict__ latent,
                                                      const float* __restrict__ keff32,
                                                      int* __restrict__ out,
                                                      int* __restrict__ wl_cnt,
                                                      int* __restrict__ wl) {
    int b   = blockIdx.x;            // n*64 + h
    int n   = b >> 6;
    int h   = b & 63;
    int tid = threadIdx.x;
    int w   = tid & 63;
    int m   = tid >> 6;
    int mu  = __builtin_amdgcn_readfirstlane(m);   // wave-uniform -> scalar keff loads

    const float* lp = latent + ((size_t)n * 512 + (size_t)mu * DM) * HW + (size_t)h * WW_ + w;
    float qr[DM];
#pragma unroll
    for (int d = 0; d < DM; ++d) {
        qr[d] = lp[(size_t)d * HW];
        // Opaque def: forbid rematerialization/sinking of this load -- q MUST stay
        // in a VGPR across the whole k-loop (R2/R3: compiler re-fetched q in-loop).
        asm volatile("" : "+v"(qr[d]));
    }

    const float* kp = keff32 + (size_t)mu * KC * DM;

    float bestv = -3.0e38f, secondv = -3.0e38f;
    int   best  = 0;
    for (int k = 0; k < KC; k += 4) {
        const float* r0 = kp + (size_t)k * DM;
        const float* r1 = r0 + DM;
        const float* r2 = r1 + DM;
        const float* r3 = r2 + DM;
        float s0 = 0.f, s1 = 0.f, s2 = 0.f, s3 = 0.f;
#pragma unroll
        for (int d = 0; d < DM; ++d) {
            float qd = qr[d];
            s0 = fmaf(qd, r0[d], s0);
            s1 = fmaf(qd, r1[d], s1);
            s2 = fmaf(qd, r2[d], s2);
            s3 = fmaf(qd, r3[d], s3);
        }
        // ascending k + strict '>' == first-occurrence argmax; track runner-up
        if (s0 > bestv) { secondv = bestv; bestv = s0; best = k;     } else if (s0 > secondv) secondv = s0;
        if (s1 > bestv) { secondv = bestv; bestv = s1; best = k + 1; } else if (s1 > secondv) secondv = s1;
        if (s2 > bestv) { secondv = bestv; bestv = s2; best = k + 2; } else if (s2 > secondv) secondv = s2;
        if (s3 > bestv) { secondv = bestv; bestv = s3; best = k + 3; } else if (s3 > secondv) secondv = s3;
    }

    int pix = ((b * WW_ + w) * MM) + m;   // n,h,w,m flat index
    out[pix] = best;

    if (bestv - secondv < EPS) {
        int slot = atomicAdd(wl_cnt, 1);
        if (slot < WL_CAP) wl[slot] = pix;
    }
}

// ---- Kernel 4: fp64 rescue of flagged pixel-groups ----
__global__ __launch_bounds__(256) void rescue_kernel(const float* __restrict__ latent,
                                                     const double* __restrict__ keffd,
                                                     const int* __restrict__ wl_cnt,
                                                     const int* __restrict__ wl,
                                                     int* __restrict__ out) {
    __shared__ double svals[256];
    __shared__ int    sidx[256];
    int cnt = *wl_cnt;
    if (cnt > WL_CAP) cnt = WL_CAP;
    int t = threadIdx.x;
    for (int i = blockIdx.x; i < cnt; i += gridDim.x) {
        int pix = wl[i];
        int m   = pix & 3;
        int rem = pix >> 2;          // (n*64+h)*64 + w
        int w   = rem & 63;
        int bh  = rem >> 6;          // n*64+h
        int n   = bh >> 6;
        int h   = bh & 63;
        const float*  lp = latent + ((size_t)n * 512 + (size_t)m * DM) * HW + (size_t)h * WW_ + w;
        const double* kr = keffd + ((size_t)m * KC + t) * DM;
        double s = 0.0;
        for (int d = 0; d < DM; ++d)
            s = fma((double)lp[(size_t)d * HW], kr[d], s);
        svals[t] = s;
        sidx[t]  = t;
        __syncthreads();
        for (int stp = 128; stp > 0; stp >>= 1) {
            if (t < stp) {
                double vo = svals[t + stp], vm = svals[t];
                int io = sidx[t + stp], im = sidx[t];
                if (vo > vm || (vo == vm && io < im)) { svals[t] = vo; sidx[t] = io; }
            }
            __syncthreads();
        }
        if (t == 0) out[pix] = sidx[0];
        __syncthreads();
    }
}

extern "C" void kernel_launch(void* const* d_in, const int* in_sizes, int n_in,
                              void* d_out, int out_size, void* d_ws, size_t ws_size,
                              hipStream_t stream) {
    const float* latent = (const float*)d_in[0];   // [16,512,64,64]
    const float* cb     = (const float*)d_in[1];   // [4,256,128]
    const float* wq     = (const float*)d_in[2];   // [4,128,128]
    const float* wk     = (const float*)d_in[3];   // [4,128,128]
    int* out = (int*)d_out;                        // 262144 code indices (int32)

    // workspace layout
    char* ws = (char*)d_ws;
    double* A       = (double*)ws;                          ws += (size_t)MM * DM * DM * sizeof(double);   // 512 KB
    double* keffd   = (double*)ws;                          ws += (size_t)MM * KC * DM * sizeof(double);   // 1 MB
    float*  keff32  = (float*)ws;                           ws += (size_t)MM * KC * DM * sizeof(float);    // 512 KB
    int*    wl_cnt  = (int*)ws;                             ws += 256;
    int*    wl      = (int*)ws;                              // WL_CAP * 4 = 256 KB

    hipMemsetAsync(wl_cnt, 0, sizeof(int), stream);
    a_kernel<<<MM * DM, 128, 0, stream>>>(wk, wq, A);
    keff_kernel<<<MM * KC, 128, 0, stream>>>(cb, A, keffd, keff32);
    argmax_fast<<<NTOT * HH, 256, 0, stream>>>(latent, keff32, out, wl_cnt, wl);
    rescue_kernel<<<256, 256, 0, stream>>>(latent, keffd, wl_cnt, wl, out);
}

// Round 6
// 438.565 us; speedup vs baseline: 2.7680x; 2.7680x over previous
//
#include <hip/hip_runtime.h>

// QuantizerEncoder: code[n,h,w,m] = argmax_k < wq[m] @ q_raw[n,h,w,m], wk[m] @ cb[m,k] >
// n=16, d=512, h=64, w=64, m=4, kcodes=256, dm=128
//
// Round 5: MFMA route. scores = q @ keff^T is a GEMM (M=262144, N=256, K=128).
//  - prep: A = wk^T wq (fp64); keff = cb @ A (fp64 master + fp16 copy)
//  - main: mfma_f32_16x16x32_f16. Block = one (n,h,m) row (64 pixels).
//    q staged NCHW->LDS[w][d] fp16 (+16B row pad); per wave: 16 pixels x 256 codes,
//    A-frags from LDS, B-frags from L2-resident keff16, 64 MFMAs -> 64 acc regs.
//    Epilogue: best/second argmax via 16-lane shfl_xor, tie -> lowest code.
//    gap < EPS (=10 sigma of fp16 path error) -> worklist.
//  - rescue: canonical fp64 re-argmax of flagged pixels (q via LDS, 4-way unroll).
// R2-R4 lesson: scalar-VALU path is allocator-hostile (compiler refuses to keep
// q[128] in VGPRs); MFMA holds state in accumulators instead.

#define MM   4
#define KC   256
#define DM   128
#define HW   4096   // h*w
#define WW_  64
#define EPS  0.045f
#define WL_CAP 65536
#define RS   136    // LDS row stride in halfs: 128 + 8 pad (16B) -> breaks bank aliasing

typedef _Float16 f16x8 __attribute__((ext_vector_type(8)));
typedef float    f32x4 __attribute__((ext_vector_type(4)));

// ---- Kernel 1: A[m][e][d] = sum_c wk[m][c][e] * wq[m][c][d]  (fp64) ----
__global__ __launch_bounds__(128) void a_kernel(const float* __restrict__ wk,
                                                const float* __restrict__ wq,
                                                double* __restrict__ A) {
    int me = blockIdx.x;           // m*128 + e
    int d  = threadIdx.x;
    int m  = me >> 7;
    int e  = me & 127;
    const float* wkm = wk + (size_t)m * DM * DM + e;       // wk[m][c][e], stride DM
    const float* wqm = wq + (size_t)m * DM * DM + d;       // wq[m][c][d], stride DM
    double s0 = 0.0, s1 = 0.0, s2 = 0.0, s3 = 0.0;
#pragma unroll 8
    for (int c = 0; c < DM; c += 4) {
        s0 = fma((double)wkm[(size_t)(c+0) * DM], (double)wqm[(size_t)(c+0) * DM], s0);
        s1 = fma((double)wkm[(size_t)(c+1) * DM], (double)wqm[(size_t)(c+1) * DM], s1);
        s2 = fma((double)wkm[(size_t)(c+2) * DM], (double)wqm[(size_t)(c+2) * DM], s2);
        s3 = fma((double)wkm[(size_t)(c+3) * DM], (double)wqm[(size_t)(c+3) * DM], s3);
    }
    A[(size_t)me * DM + d] = (s0 + s1) + (s2 + s3);
}

// ---- Kernel 2: keff[m][k][d] = sum_e cb[m][k][e] * A[m][e][d]  (fp64 + fp16 copy) ----
__global__ __launch_bounds__(128) void keff_kernel(const float* __restrict__ cb,
                                                   const double* __restrict__ A,
                                                   double* __restrict__ keffd,
                                                   _Float16* __restrict__ keff16) {
    int mk = blockIdx.x;           // m*256 + k
    int d  = threadIdx.x;
    int m  = mk >> 8;
    const float*  cbr = cb + (size_t)mk * DM;              // cb[m][k][*]
    const double* Am  = A + (size_t)m * DM * DM + d;       // A[m][e][d], stride DM
    double s0 = 0.0, s1 = 0.0, s2 = 0.0, s3 = 0.0;
#pragma unroll 8
    for (int e = 0; e < DM; e += 4) {
        s0 = fma((double)cbr[e+0], Am[(size_t)(e+0) * DM], s0);
        s1 = fma((double)cbr[e+1], Am[(size_t)(e+1) * DM], s1);
        s2 = fma((double)cbr[e+2], Am[(size_t)(e+2) * DM], s2);
        s3 = fma((double)cbr[e+3], Am[(size_t)(e+3) * DM], s3);
    }
    double s = (s0 + s1) + (s2 + s3);
    keffd[(size_t)mk * DM + d]  = s;
    keff16[(size_t)mk * DM + d] = (_Float16)s;
}

// ---- Kernel 3: MFMA argmax ----
// grid = 4096 blocks: blk = nh*4 + m; block = 256 threads (4 waves).
// Wave v computes pixels w = v*16..v*16+15 vs all 256 codes.
__global__ __launch_bounds__(256, 3) void argmax_mfma(const float* __restrict__ latent,
                                                      const _Float16* __restrict__ keff16,
                                                      int* __restrict__ out,
                                                      int* __restrict__ wl_cnt,
                                                      int* __restrict__ wl) {
    __shared__ _Float16 lq[64 * RS];   // q tile: [w][d], padded rows

    int blk  = blockIdx.x;         // 0..4095
    int m    = blk & 3;
    int nh   = blk >> 2;           // n*64 + h
    int n    = nh >> 6;
    int h    = nh & 63;
    int tid  = threadIdx.x;
    int wave = tid >> 6;
    int lane = tid & 63;
    int col  = lane & 15;          // MFMA n-index (code within tile) / A row (pixel)
    int quad = lane >> 4;          // MFMA k-octet selector

    // ---- stage q: latent[n][m*128+d][h][w] -> lq[w][d] (fp16) ----
    {
        int w  = tid & 63;
        int d0 = tid >> 6;
        const float* lp = latent + ((size_t)(n * 512 + m * DM)) * HW + h * WW_ + w;
        for (int d = d0; d < DM; d += 4)
            lq[w * RS + d] = (_Float16)lp[(size_t)d * HW];   // coalesced 256B per wave-row
    }
    __syncthreads();

    // ---- A fragments (held across all 16 code tiles) ----
    // A[mrow = lane&15][k = quad*8 + j], mrow = pixel within wave tile
    f16x8 Af[4];
#pragma unroll
    for (int st = 0; st < 4; ++st)
        Af[st] = *(const f16x8*)&lq[(wave * 16 + col) * RS + st * 32 + quad * 8];

    f32x4 acc[16];
#pragma unroll
    for (int t = 0; t < 16; ++t) acc[t] = (f32x4){0.f, 0.f, 0.f, 0.f};

    // ---- K-loop over 16 code tiles; B direct from L2-resident keff16 ----
    const _Float16* kb = keff16 + (size_t)m * KC * DM;
    for (int t = 0; t < 16; ++t) {
        const _Float16* bp = kb + (size_t)(t * 16 + col) * DM + quad * 8;
        f16x8 B0 = *(const f16x8*)(bp);
        f16x8 B1 = *(const f16x8*)(bp + 32);
        f16x8 B2 = *(const f16x8*)(bp + 64);
        f16x8 B3 = *(const f16x8*)(bp + 96);
        f32x4 c = acc[t];
        c = __builtin_amdgcn_mfma_f32_16x16x32_f16(Af[0], B0, c, 0, 0, 0);
        c = __builtin_amdgcn_mfma_f32_16x16x32_f16(Af[1], B1, c, 0, 0, 0);
        c = __builtin_amdgcn_mfma_f32_16x16x32_f16(Af[2], B2, c, 0, 0, 0);
        c = __builtin_amdgcn_mfma_f32_16x16x32_f16(Af[3], B3, c, 0, 0, 0);
        acc[t] = c;
    }

    // ---- epilogue: per pixel-row argmax with runner-up, 16-lane shfl_xor merge ----
    // C/D layout: col = lane&15 (code), row = quad*4 + reg (pixel). Codes for pixel p
    // live on the 16 lanes of quad p>>2, as acc[t][p&3], code = t*16 + col.
#pragma unroll
    for (int r = 0; r < 4; ++r) {
        float bv = acc[0][r];
        int   bi = col;
        float sv = -3.0e38f;
#pragma unroll
        for (int t = 1; t < 16; ++t) {
            float v = acc[t][r];
            int idx = t * 16 + col;               // ascending within lane
            if (v > bv) { sv = bv; bv = v; bi = idx; }
            else if (v > sv) sv = v;
        }
#pragma unroll
        for (int off = 1; off < 16; off <<= 1) {  // stays within 16-lane groups
            float obv = __shfl_xor(bv, off);
            int   obi = __shfl_xor(bi, off);
            float osv = __shfl_xor(sv, off);
            bool  take = (obv > bv) || (obv == bv && obi < bi);
            float loser = take ? bv : obv;
            float nsv = fmaxf(loser, fmaxf(sv, osv));
            if (take) { bv = obv; bi = obi; }
            sv = nsv;
        }
        if (col == 0) {
            int wpix = wave * 16 + quad * 4 + r;
            int pix  = (nh * WW_ + wpix) * MM + m;
            out[pix] = bi;
            if (bv - sv < EPS) {
                int slot = atomicAdd(wl_cnt, 1);
                if (slot < WL_CAP) wl[slot] = pix;
            }
        }
    }
}

// ---- Kernel 4: fp64 canonical rescue of flagged pixel-groups ----
__global__ __launch_bounds__(256) void rescue_kernel(const float* __restrict__ latent,
                                                     const double* __restrict__ keffd,
                                                     const int* __restrict__ wl_cnt,
                                                     const int* __restrict__ wl,
                                                     int* __restrict__ out) {
    __shared__ double sq[DM];
    __shared__ double svals[256];
    __shared__ int    sidx[256];
    int cnt = *wl_cnt;
    if (cnt > WL_CAP) cnt = WL_CAP;
    int t = threadIdx.x;
    for (int i = blockIdx.x; i < cnt; i += gridDim.x) {
        int pix = wl[i];
        int m   = pix & 3;
        int rem = pix >> 2;          // (n*64+h)*64 + w
        int w   = rem & 63;
        int bh  = rem >> 6;          // n*64+h
        int n   = bh >> 6;
        int h   = bh & 63;
        const float* lp = latent + ((size_t)(n * 512 + m * DM)) * HW + h * WW_ + w;
        if (t < DM) sq[t] = (double)lp[(size_t)t * HW];
        __syncthreads();
        const double* kr = keffd + ((size_t)m * KC + t) * DM;
        double s0 = 0.0, s1 = 0.0, s2 = 0.0, s3 = 0.0;
#pragma unroll 8
        for (int d = 0; d < DM; d += 4) {
            s0 = fma(sq[d+0], kr[d+0], s0);
            s1 = fma(sq[d+1], kr[d+1], s1);
            s2 = fma(sq[d+2], kr[d+2], s2);
            s3 = fma(sq[d+3], kr[d+3], s3);
        }
        svals[t] = (s0 + s1) + (s2 + s3);
        sidx[t]  = t;
        __syncthreads();
        for (int stp = 128; stp > 0; stp >>= 1) {
            if (t < stp) {
                double vo = svals[t + stp], vm = svals[t];
                int io = sidx[t + stp], im = sidx[t];
                if (vo > vm || (vo == vm && io < im)) { svals[t] = vo; sidx[t] = io; }
            }
            __syncthreads();
        }
        if (t == 0) out[pix] = sidx[0];
        __syncthreads();
    }
}

extern "C" void kernel_launch(void* const* d_in, const int* in_sizes, int n_in,
                              void* d_out, int out_size, void* d_ws, size_t ws_size,
                              hipStream_t stream) {
    const float* latent = (const float*)d_in[0];   // [16,512,64,64]
    const float* cb     = (const float*)d_in[1];   // [4,256,128]
    const float* wq     = (const float*)d_in[2];   // [4,128,128]
    const float* wk     = (const float*)d_in[3];   // [4,128,128]
    int* out = (int*)d_out;                        // 262144 code indices (int32)

    // workspace layout
    char* ws = (char*)d_ws;
    double*   A      = (double*)ws;     ws += (size_t)MM * DM * DM * sizeof(double);    // 512 KB
    double*   keffd  = (double*)ws;     ws += (size_t)MM * KC * DM * sizeof(double);    // 1 MB
    _Float16* keff16 = (_Float16*)ws;   ws += (size_t)MM * KC * DM * sizeof(_Float16);  // 256 KB
    int*      wl_cnt = (int*)ws;        ws += 256;
    int*      wl     = (int*)ws;        // WL_CAP * 4 = 256 KB

    hipMemsetAsync(wl_cnt, 0, sizeof(int), stream);
    a_kernel<<<MM * DM, 128, 0, stream>>>(wk, wq, A);
    keff_kernel<<<MM * KC, 128, 0, stream>>>(cb, A, keffd, keff16);
    argmax_mfma<<<4096, 256, 0, stream>>>(latent, keff16, out, wl_cnt, wl);
    rescue_kernel<<<256, 256, 0, stream>>>(latent, keffd, wl_cnt, wl, out);
}

// Round 7
// 353.212 us; speedup vs baseline: 3.4369x; 1.2416x over previous
//
#include <hip/hip_runtime.h>

// QuantizerEncoder: code[n,h,w,m] = argmax_k < wq[m] @ q_raw[n,h,w,m], wk[m] @ cb[m,k] >
// n=16, d=512, h=64, w=64, m=4, kcodes=256, dm=128
//
// Round 6: big-tile MFMA. R5 showed MfmaUtil 3.6% -- all latency/overhead.
//  - 512 blocks (n x m x 8 h-groups), 4 waves; each block does 8 rows (512 pixels).
//  - keff (codes) = MFMA *A* operand, held in 64 VGPRs per wave (loaded once).
//    Pixels = B operand from double-buffered LDS (fp16, row stride 132 halfs:
//    ushort2 writes 2-way conflict-free, b64-aligned frag reads).
//  - C layout: col=lane&15 -> pixel, row=quad*4+reg -> code. A pixel's 64 wave-codes
//    live on 4 lanes -> epilogue = 16-value in-lane scan + 2 shfl_xor merges,
//    then tiny cross-wave LDS merge. gap < EPS -> canonical fp64 rescue.
//  - rescue reads transposed keffdT (coalesced; R5's version had lanes 1KB apart).

#define MM   4
#define KC   256
#define DM   128
#define HW   4096   // h*w
#define WW_  64
#define EPS  0.045f
#define WL_CAP 65536
#define RSH  132    // LDS row stride in halfs (264B)

typedef _Float16 f16x8 __attribute__((ext_vector_type(8)));
typedef _Float16 f16x4 __attribute__((ext_vector_type(4)));
typedef _Float16 f16x2 __attribute__((ext_vector_type(2)));
typedef float    f32x4 __attribute__((ext_vector_type(4)));

// ---- Kernel 1: A[m][e][d] = sum_c wk[m][c][e] * wq[m][c][d]  (fp64) ----
__global__ __launch_bounds__(128) void a_kernel(const float* __restrict__ wk,
                                                const float* __restrict__ wq,
                                                double* __restrict__ A) {
    int me = blockIdx.x;           // m*128 + e
    int d  = threadIdx.x;
    int m  = me >> 7;
    int e  = me & 127;
    const float* wkm = wk + (size_t)m * DM * DM + e;       // wk[m][c][e], stride DM
    const float* wqm = wq + (size_t)m * DM * DM + d;       // wq[m][c][d], stride DM
    double s0 = 0.0, s1 = 0.0, s2 = 0.0, s3 = 0.0;
#pragma unroll 8
    for (int c = 0; c < DM; c += 4) {
        s0 = fma((double)wkm[(size_t)(c+0) * DM], (double)wqm[(size_t)(c+0) * DM], s0);
        s1 = fma((double)wkm[(size_t)(c+1) * DM], (double)wqm[(size_t)(c+1) * DM], s1);
        s2 = fma((double)wkm[(size_t)(c+2) * DM], (double)wqm[(size_t)(c+2) * DM], s2);
        s3 = fma((double)wkm[(size_t)(c+3) * DM], (double)wqm[(size_t)(c+3) * DM], s3);
    }
    A[(size_t)me * DM + d] = (s0 + s1) + (s2 + s3);
}

// ---- Kernel 2: keff[m][k][d] = sum_e cb[m][k][e]*A[m][e][d]; store fp16 + fp64-transposed ----
__global__ __launch_bounds__(128) void keff_kernel(const float* __restrict__ cb,
                                                   const double* __restrict__ A,
                                                   double* __restrict__ keffdT,
                                                   _Float16* __restrict__ keff16) {
    int mk = blockIdx.x;           // m*256 + k
    int d  = threadIdx.x;
    int m  = mk >> 8;
    int k  = mk & 255;
    const float*  cbr = cb + (size_t)mk * DM;              // cb[m][k][*]
    const double* Am  = A + (size_t)m * DM * DM + d;       // A[m][e][d], stride DM
    double s0 = 0.0, s1 = 0.0, s2 = 0.0, s3 = 0.0;
#pragma unroll 8
    for (int e = 0; e < DM; e += 4) {
        s0 = fma((double)cbr[e+0], Am[(size_t)(e+0) * DM], s0);
        s1 = fma((double)cbr[e+1], Am[(size_t)(e+1) * DM], s1);
        s2 = fma((double)cbr[e+2], Am[(size_t)(e+2) * DM], s2);
        s3 = fma((double)cbr[e+3], Am[(size_t)(e+3) * DM], s3);
    }
    double s = (s0 + s1) + (s2 + s3);
    keffdT[((size_t)m * DM + d) * KC + k] = s;             // transposed: rescue reads coalesced
    keff16[(size_t)mk * DM + d] = (_Float16)s;
}

// ---- Kernel 3: MFMA argmax, 8 rows per block ----
__global__ __launch_bounds__(256, 2) void argmax_mfma(const float* __restrict__ latent,
                                                      const _Float16* __restrict__ keff16,
                                                      int* __restrict__ out,
                                                      int* __restrict__ wl_cnt,
                                                      int* __restrict__ wl) {
    __shared__ _Float16 lq[2][64 * RSH];   // 2 x 16,896 B q tiles
    __shared__ float pbv[64][4];
    __shared__ float psv[64][4];
    __shared__ int   pbi[64][4];

    int blk  = blockIdx.x;          // 0..511 = n(16) x m(4) x hg(8)
    int n    = blk >> 5;
    int m    = (blk >> 3) & 3;
    int hg   = blk & 7;
    int tid  = threadIdx.x;
    int wave = tid >> 6;
    int lane = tid & 63;
    int col  = lane & 15;
    int quad = lane >> 4;
    int w    = tid & 63;
    int pb_  = tid >> 6;            // staging pair-base 0..3

    // ---- A-frags: this wave's 64 codes, resident in 64 VGPRs for the whole block ----
    // A[mrow=code (lane&15 within tile)][k = quad*8+j]
    f16x8 Af[4][4];
    {
        const _Float16* kbase = keff16 + ((size_t)m * KC + wave * 64) * DM;
#pragma unroll
        for (int t = 0; t < 4; ++t)
#pragma unroll
            for (int s = 0; s < 4; ++s)
                Af[t][s] = *(const f16x8*)(kbase + (size_t)(t * 16 + col) * DM + s * 32 + quad * 8);
    }

    const float* lp0 = latent + ((size_t)(n * 512 + m * DM)) * HW + (size_t)(hg * 8) * WW_ + w;

    // ---- stage row 0 ----
#pragma unroll
    for (int i = 0; i < 16; ++i) {
        int d = 2 * (pb_ + 4 * i);
        float a = lp0[(size_t)d * HW];
        float b = lp0[(size_t)(d + 1) * HW];
        f16x2 pk; pk[0] = (_Float16)a; pk[1] = (_Float16)b;
        *(f16x2*)&lq[0][w * RSH + d] = pk;      // 2-way bank aliasing: free
    }
    __syncthreads();

    for (int r = 0; r < 8; ++r) {
        int cur = r & 1;

        // ---- prefetch next row into registers (fp16-packed, 16 VGPRs) ----
        f16x2 pf[16];
        if (r < 7) {
            const float* lp = lp0 + (size_t)(r + 1) * WW_;
#pragma unroll
            for (int i = 0; i < 16; ++i) {
                int d = 2 * (pb_ + 4 * i);
                float a = lp[(size_t)d * HW];
                float b = lp[(size_t)(d + 1) * HW];
                pf[i][0] = (_Float16)a; pf[i][1] = (_Float16)b;
            }
        }

        // ---- compute: 4 pixel-tiles x 4 code-tiles x 4 K-steps = 64 MFMAs ----
        f32x4 acc[4][4];
#pragma unroll
        for (int p = 0; p < 4; ++p) {
            f16x8 Bf[4];
#pragma unroll
            for (int s = 0; s < 4; ++s) {
                const _Float16* bp = &lq[cur][(size_t)(p * 16 + col) * RSH + s * 32 + quad * 8];
                f16x4 lo = *(const f16x4*)bp;
                f16x4 hi = *(const f16x4*)(bp + 4);
                Bf[s] = __builtin_shufflevector(lo, hi, 0, 1, 2, 3, 4, 5, 6, 7);
            }
#pragma unroll
            for (int t = 0; t < 4; ++t) {
                f32x4 c = (f32x4){0.f, 0.f, 0.f, 0.f};
                c = __builtin_amdgcn_mfma_f32_16x16x32_f16(Af[t][0], Bf[0], c, 0, 0, 0);
                c = __builtin_amdgcn_mfma_f32_16x16x32_f16(Af[t][1], Bf[1], c, 0, 0, 0);
                c = __builtin_amdgcn_mfma_f32_16x16x32_f16(Af[t][2], Bf[2], c, 0, 0, 0);
                c = __builtin_amdgcn_mfma_f32_16x16x32_f16(Af[t][3], Bf[3], c, 0, 0, 0);
                acc[p][t] = c;
            }
        }

        // ---- epilogue: C col=pixel-in-tile, row=quad*4+reg=code-in-tile ----
#pragma unroll
        for (int p = 0; p < 4; ++p) {
            float bv = acc[p][0][0];
            int   bi = wave * 64 + quad * 4;
            float sv = -3.0e38f;
#pragma unroll
            for (int t = 0; t < 4; ++t)
#pragma unroll
                for (int g = 0; g < 4; ++g) {
                    if (t == 0 && g == 0) continue;
                    float v   = acc[p][t][g];
                    int   idx = wave * 64 + t * 16 + quad * 4 + g;   // ascending scan
                    if (v > bv)      { sv = bv; bv = v; bi = idx; }
                    else if (v > sv) sv = v;
                }
            // merge across the 4 quads holding this pixel
#pragma unroll
            for (int off = 16; off < 64; off <<= 1) {
                float ov = __shfl_xor(bv, off);
                int   oi = __shfl_xor(bi, off);
                float os = __shfl_xor(sv, off);
                bool  take  = (ov > bv) || (ov == bv && oi < bi);
                float loser = take ? bv : ov;
                sv = fmaxf(fmaxf(sv, os), loser);
                if (take) { bv = ov; bi = oi; }
            }
            if (quad == 0) {
                int P = p * 16 + col;
                pbv[P][wave] = bv; psv[P][wave] = sv; pbi[P][wave] = bi;
            }
        }
        __syncthreads();

        // ---- cross-wave merge + output (64 threads), staging write (all) ----
        if (tid < 64) {
            int   P  = tid;
            float bv = pbv[P][0]; float sv = psv[P][0]; int bi = pbi[P][0];
#pragma unroll
            for (int wv = 1; wv < 4; ++wv) {
                float ov = pbv[P][wv]; float os = psv[P][wv]; int oi = pbi[P][wv];
                bool  take  = (ov > bv) || (ov == bv && oi < bi);
                float loser = take ? bv : ov;
                sv = fmaxf(fmaxf(sv, os), loser);
                if (take) { bv = ov; bi = oi; }
            }
            int h   = hg * 8 + r;
            int pix = (((n * 64 + h) * 64) + P) * MM + m;
            out[pix] = bi;
            if (bv - sv < EPS) {
                int slot = atomicAdd(wl_cnt, 1);
                if (slot < WL_CAP) wl[slot] = pix;
            }
        }
        if (r < 7) {
#pragma unroll
            for (int i = 0; i < 16; ++i) {
                int d = 2 * (pb_ + 4 * i);
                *(f16x2*)&lq[cur ^ 1][w * RSH + d] = pf[i];
            }
        }
        __syncthreads();
    }
}

// ---- Kernel 4: fp64 canonical rescue (coalesced keffdT reads) ----
__global__ __launch_bounds__(256) void rescue_kernel(const float* __restrict__ latent,
                                                     const double* __restrict__ keffdT,
                                                     const int* __restrict__ wl_cnt,
                                                     const int* __restrict__ wl,
                                                     int* __restrict__ out) {
    __shared__ double sq[DM];
    __shared__ double svals[256];
    __shared__ int    sidx[256];
    int cnt = *wl_cnt;
    if (cnt > WL_CAP) cnt = WL_CAP;
    int t = threadIdx.x;
    for (int i = blockIdx.x; i < cnt; i += gridDim.x) {
        int pix = wl[i];
        int m   = pix & 3;
        int rem = pix >> 2;          // (n*64+h)*64 + w
        int w   = rem & 63;
        int bh  = rem >> 6;          // n*64+h
        int n   = bh >> 6;
        int h   = bh & 63;
        const float* lp = latent + ((size_t)(n * 512 + m * DM)) * HW + h * WW_ + w;
        if (t < DM) sq[t] = (double)lp[(size_t)t * HW];
        __syncthreads();
        const double* kr = keffdT + (size_t)m * DM * KC + t;   // [d][k=t]: lanes coalesced
        double s0 = 0.0, s1 = 0.0, s2 = 0.0, s3 = 0.0;
#pragma unroll 8
        for (int d = 0; d < DM; d += 4) {
            s0 = fma(sq[d+0], kr[(size_t)(d+0) * KC], s0);
            s1 = fma(sq[d+1], kr[(size_t)(d+1) * KC], s1);
            s2 = fma(sq[d+2], kr[(size_t)(d+2) * KC], s2);
            s3 = fma(sq[d+3], kr[(size_t)(d+3) * KC], s3);
        }
        svals[t] = (s0 + s1) + (s2 + s3);
        sidx[t]  = t;
        __syncthreads();
        for (int stp = 128; stp > 0; stp >>= 1) {
            if (t < stp) {
                double vo = svals[t + stp], vm = svals[t];
                int io = sidx[t + stp], im = sidx[t];
                if (vo > vm || (vo == vm && io < im)) { svals[t] = vo; sidx[t] = io; }
            }
            __syncthreads();
        }
        if (t == 0) out[pix] = sidx[0];
        __syncthreads();
    }
}

extern "C" void kernel_launch(void* const* d_in, const int* in_sizes, int n_in,
                              void* d_out, int out_size, void* d_ws, size_t ws_size,
                              hipStream_t stream) {
    const float* latent = (const float*)d_in[0];   // [16,512,64,64]
    const float* cb     = (const float*)d_in[1];   // [4,256,128]
    const float* wq     = (const float*)d_in[2];   // [4,128,128]
    const float* wk     = (const float*)d_in[3];   // [4,128,128]
    int* out = (int*)d_out;                        // 262144 code indices (int32)

    // workspace layout (~2.1 MB)
    char* ws = (char*)d_ws;
    double*   A      = (double*)ws;     ws += (size_t)MM * DM * DM * sizeof(double);    // 512 KB
    double*   keffdT = (double*)ws;     ws += (size_t)MM * DM * KC * sizeof(double);    // 1 MB
    _Float16* keff16 = (_Float16*)ws;   ws += (size_t)MM * KC * DM * sizeof(_Float16);  // 256 KB
    int*      wl_cnt = (int*)ws;        ws += 256;
    int*      wl     = (int*)ws;        // WL_CAP * 4 = 256 KB

    hipMemsetAsync(wl_cnt, 0, sizeof(int), stream);
    a_kernel<<<MM * DM, 128, 0, stream>>>(wk, wq, A);
    keff_kernel<<<MM * KC, 128, 0, stream>>>(cb, A, keffdT, keff16);
    argmax_mfma<<<512, 256, 0, stream>>>(latent, keff16, out, wl_cnt, wl);
    rescue_kernel<<<256, 256, 0, stream>>>(latent, keffdT, wl_cnt, wl, out);
}